// Round 5
// baseline (149.149 us; speedup 1.0000x reference)
//
#include <hip/hip_runtime.h>
#include <hip/hip_bf16.h>

typedef __attribute__((ext_vector_type(8))) short short8;
typedef __attribute__((ext_vector_type(4))) short short4v;
typedef __attribute__((ext_vector_type(4))) float f32x4;

#define D_MODEL 1024
#define N_HEADS 16
#define D_KK 64
#define BATCH 4
#define SEQ 1024
#define NTOK (BATCH*SEQ)

#define LOG2E  1.44269504f
#define SCALE2 (0.125f * 1.44269504f)
#define NEGBIG (-1.44269504e9f)

#if __has_builtin(__builtin_amdgcn_mfma_f32_16x16x16bf16_1k)
#define HAVE_MFMA16 1
#else
#define HAVE_MFMA16 0
#endif

// round-to-nearest-even f32 -> bf16 (bit pattern in short)
__device__ __forceinline__ short f2b(float f){
  unsigned u = __float_as_uint(f);
  u += 0x7fffu + ((u >> 16) & 1u);
  return (short)(u >> 16);
}

__device__ __forceinline__ void gl2lds16(const void* g, void* l){
  __builtin_amdgcn_global_load_lds(
      (const __attribute__((address_space(1))) void*)g,
      (__attribute__((address_space(3))) void*)l, 16, 0, 0);
}

// ---------------- fused f32 -> bf16 conversion (x, wq, wk, wv, wo) ----------
__global__ __launch_bounds__(256) void cvt_all_kernel(
    const float* __restrict__ x,  const float* __restrict__ wq,
    const float* __restrict__ wk, const float* __restrict__ wv,
    const float* __restrict__ wo, short* __restrict__ dst)
{
  const size_t NX = (size_t)NTOK * D_MODEL;
  const size_t NW = (size_t)D_MODEL * D_MODEL;
  size_t e = ((size_t)blockIdx.x * 256 + threadIdx.x) * 4;
  const float* s;
  size_t off;
  if      (e < NX)        { s = x;  off = e; }
  else if (e < NX +   NW) { s = wq; off = e - NX; }
  else if (e < NX + 2*NW) { s = wk; off = e - NX -   NW; }
  else if (e < NX + 3*NW) { s = wv; off = e - NX - 2*NW; }
  else                    { s = wo; off = e - NX - 3*NW; }
  f32x4 v = *reinterpret_cast<const f32x4*>(s + off);
  short4v o;
  o[0]=f2b(v[0]); o[1]=f2b(v[1]); o[2]=f2b(v[2]); o[3]=f2b(v[3]);
  *reinterpret_cast<short4v*>(dst + e) = o;
}

// ---------------- GEMM: C[M,N] = A[M,K] @ W[N,K]^T + bias ----------------
// 128xBN tile, BK=64, XOR-swizzled LDS (conflict-free b128 reads), 4 waves.
// MODE 0: bf16 row-major out. MODE 1: f32 row-major out.
// MODE 2: bf16 out transposed per head: Out[((b*16+h)*64 + d)*SEQ + s]
template<int BN, int MODE>
__device__ __forceinline__ void gemm_bt_body(const short* __restrict__ A,
    const short* __restrict__ W, const float* __restrict__ bias,
    void* __restrict__ Cout, int N, int K)
{
  constexpr int NF = BN / 32;          // B-frags per wave (wave N-width = BN/2)
  __shared__ short As[128][64];
  __shared__ short Bs[BN][64];
  const int tid = threadIdx.x, lane = tid & 63, w = tid >> 6;
  const int wr = w >> 1, wc = w & 1;
  const int bn0 = blockIdx.x * BN, bm0 = blockIdx.y * 128;
  const int srow = lane >> 3;                 // row within 8-row chunk
  const int scol = ((lane & 7) ^ srow) * 8;   // pre-swizzled 16B source column
  const int fr = lane & 15, g = lane >> 4;

  f32x4 acc[4][NF];
  #pragma unroll
  for (int m=0;m<4;m++)
    #pragma unroll
    for (int n=0;n<NF;n++) acc[m][n] = (f32x4){0.f,0.f,0.f,0.f};

  for (int k0 = 0; k0 < K; k0 += 64){
    __syncthreads();
    #pragma unroll
    for (int i=0;i<4;i++){                    // A: 16 chunks of 8 rows
      const int c = w*4 + i;
      gl2lds16(A + (size_t)(bm0 + c*8 + srow)*K + k0 + scol, &As[c*8][0]);
    }
    #pragma unroll
    for (int i=0;i<NF;i++){                   // B: BN/8 chunks
      const int c = w*NF + i;
      gl2lds16(W + (size_t)(bn0 + c*8 + srow)*K + k0 + scol, &Bs[c*8][0]);
    }
    __syncthreads();
    #pragma unroll
    for (int f=0; f<2; f++){
      short8 af[4], bfr[NF];
      #pragma unroll
      for (int m=0;m<4;m++){
        const int rr = wr*64 + m*16 + fr;
        af[m] = *reinterpret_cast<const short8*>(
            (const char*)&As[0][0] + rr*128 + ((g*16 + f*64) ^ ((rr&7)<<4)));
      }
      #pragma unroll
      for (int n=0;n<NF;n++){
        const int rr = wc*(BN/2) + n*16 + fr;
        bfr[n] = *reinterpret_cast<const short8*>(
            (const char*)&Bs[0][0] + rr*128 + ((g*16 + f*64) ^ ((rr&7)<<4)));
      }
      #pragma unroll
      for (int m=0;m<4;m++)
        #pragma unroll
        for (int n=0;n<NF;n++)
          acc[m][n] = __builtin_amdgcn_mfma_f32_16x16x32_bf16(af[m], bfr[n], acc[m][n], 0,0,0);
    }
  }

  #pragma unroll
  for (int n=0;n<NF;n++){
    const int col = bn0 + wc*(BN/2) + n*16 + fr;
    const float bv = bias[col];
    if (MODE == 2){
      const int hh = col >> 6, dd = col & 63;
      #pragma unroll
      for (int m=0;m<4;m++){
        const int row0 = bm0 + wr*64 + m*16 + g*4;
        const int bb = row0 >> 10, ss = row0 & 1023;
        short4v o;
        #pragma unroll
        for (int r=0;r<4;r++) o[r] = f2b(acc[m][n][r] + bv);
        *reinterpret_cast<short4v*>(
            (short*)Cout + ((size_t)(bb*N_HEADS+hh)*D_KK + dd)*SEQ + ss) = o;
      }
    } else {
      #pragma unroll
      for (int m=0;m<4;m++){
        const int row0 = bm0 + wr*64 + m*16 + g*4;
        #pragma unroll
        for (int r=0;r<4;r++){
          float v = acc[m][n][r] + bv;
          if (MODE == 1) ((float*)Cout)[(size_t)(row0+r)*N + col] = v;
          else           ((short*)Cout)[(size_t)(row0+r)*N + col] = f2b(v);
        }
      }
    }
  }
}

__global__ __launch_bounds__(256) void qkv_gemm_kernel(
    const short* __restrict__ X,
    const short* __restrict__ Wq, const short* __restrict__ Wk, const short* __restrict__ Wv,
    const float* __restrict__ bq, const float* __restrict__ bk, const float* __restrict__ bv,
    short* __restrict__ Q, short* __restrict__ K, short* __restrict__ V)
{
  const int z = blockIdx.z;
  if (z == 0)      gemm_bt_body<128,0>(X, Wq, bq, Q, D_MODEL, D_MODEL);
  else if (z == 1) gemm_bt_body<128,0>(X, Wk, bk, K, D_MODEL, D_MODEL);
  else             gemm_bt_body<128,2>(X, Wv, bv, V, D_MODEL, D_MODEL);
}

__global__ __launch_bounds__(256) void out_gemm_kernel(
    const short* __restrict__ Ctx, const short* __restrict__ Wo,
    const float* __restrict__ bo, float* __restrict__ Out)
{
  gemm_bt_body<64,1>(Ctx, Wo, bo, Out, D_MODEL, D_MODEL);
}

// ---------------- flash attention, swapped-operand, KV-split teams ---------
// 512 blocks x 512 threads (8 waves = 2 teams of 4). Team 0: keys [0,512),
// team 1: keys [512,1024), same 128 q-rows; merge (m,l,ctx) via LDS at end.
__global__ __launch_bounds__(512, 4) void attn_kernel(
    const short* __restrict__ Qb, const short* __restrict__ Kb,
    const short* __restrict__ Vtg, const int* __restrict__ mask,
    const float* __restrict__ rel_table, short* __restrict__ Ctx)
{
  const int bid = blockIdx.x;
  const int xcd = bid & 7, slot = bid >> 3;
  const int bh = xcd * 8 + (slot >> 3);      // 8 (b,h) groups per XCD
  const int qt = slot & 7;                   // 8 q-tiles of 128 rows
  const int b = bh >> 4, h = bh & 15;
  const int q0 = qt * 128;
  const int tid = threadIdx.x, lane = tid & 63, w = tid >> 6;
  const int team = w >> 2, wt = w & 3;
  const int fr = lane & 15, g = lane >> 4;

  __shared__ short kvbuf[2][2][2][64][64];  // [K/V][team][buf][row][64], swizzled
  __shared__ float rel_sh[128];             // per-head bias, pre-scaled by log2e
  __shared__ float maskf[2][2][64];         // [team][buf][key]
  __shared__ float ml[128][2];              // merge: team-1 (m,l) per q-row

  for (int i = tid; i < 127; i += 512) rel_sh[i] = rel_table[i * N_HEADS + h] * LOG2E;
  const float cb_lo = rel_table[0*N_HEADS + h]   * LOG2E;
  const float cb_hi = rel_table[126*N_HEADS + h] * LOG2E;

  const short* Qg = Qb + (size_t)b*SEQ*D_MODEL + h*D_KK;
  const short* Kg = Kb + (size_t)b*SEQ*D_MODEL + h*D_KK;
  const short* Vg = Vtg + (size_t)bh*D_KK*SEQ;     // rows = d (stride SEQ)

  // two q's per lane: frag A = q0+wt*32+fr, frag B = +16
  const int qa = q0 + wt*32 + fr;
  const int qb = qa + 16;
  short8 qfa[2], qfb[2];
  #pragma unroll
  for (int f=0; f<2; f++){
    qfa[f] = *reinterpret_cast<const short8*>(Qg + (size_t)qa*D_MODEL + g*8 + f*32);
    qfb[f] = *reinterpret_cast<const short8*>(Qg + (size_t)qb*D_MODEL + g*8 + f*32);
  }

  f32x4 ctxa[4], ctxb[4];   // ctx^T: lane holds its q, d = dt*16 + g*4 + r
  #pragma unroll
  for (int dt=0; dt<4; dt++){ ctxa[dt] = (f32x4){0.f,0.f,0.f,0.f}; ctxb[dt] = ctxa[dt]; }
  float mruna = -3.0e38f, lruna = 0.f, mrunb = -3.0e38f, lrunb = 0.f;

  const int srow = lane >> 3;
  const int scol = ((lane & 7) ^ srow) * 8;   // pre-swizzled 16B column
  auto stage = [&](int buf, int kv0){
    #pragma unroll
    for (int i=0;i<2;i++){
      const int c = wt*2 + i;
      gl2lds16(Kg + (size_t)(kv0 + c*8 + srow)*D_MODEL + scol, &kvbuf[0][team][buf][c*8][0]);
      gl2lds16(Vg + (size_t)(c*8 + srow)*SEQ + kv0 + scol,     &kvbuf[1][team][buf][c*8][0]);
    }
    if (wt == 0)
      maskf[team][buf][lane] = mask[b*SEQ + kv0 + lane] ? 1.f : 0.f;
  };

  const int kvbase = team * 512;
  stage(0, kvbase);
  __syncthreads();

  int buf = 0;
  for (int t = 0; t < 8; ++t){
    const int kv0 = kvbase + t * 64;
    if (t < 7) stage(buf ^ 1, kv0 + 64);

    // QK^T swapped: sc = K-tile · Q^T -> S^T[key][q], two q-frags share kf
    const char* ksb = (const char*)&kvbuf[0][team][buf][0][0];
    f32x4 sca[4], scb[4];
    #pragma unroll
    for (int kt=0;kt<4;kt++){
      sca[kt] = (f32x4){0.f,0.f,0.f,0.f};
      scb[kt] = (f32x4){0.f,0.f,0.f,0.f};
      const int rr = kt*16 + fr;
      const int swz = (rr & 7) << 4;
      #pragma unroll
      for (int f=0;f<2;f++){
        short8 kf = *reinterpret_cast<const short8*>(
            ksb + rr*128 + ((g*16 + f*64) ^ swz));
        sca[kt] = __builtin_amdgcn_mfma_f32_16x16x32_bf16(kf, qfa[f], sca[kt], 0,0,0);
        scb[kt] = __builtin_amdgcn_mfma_f32_16x16x32_bf16(kf, qfb[f], scb[kt], 0,0,0);
      }
    }
    // per lane: sc[kt][r] = score(key = kv0+kt*16+g*4+r, q)

    // scale + bias + mask (log2 domain)
    const int delta = kv0 - q0;
    if (delta <= -128 || delta >= 192){
      const float cb = (delta > 0) ? cb_hi : cb_lo;
      #pragma unroll
      for (int kt=0;kt<4;kt++){
        f32x4 mk4 = *reinterpret_cast<const f32x4*>(&maskf[team][buf][kt*16 + g*4]);
        #pragma unroll
        for (int r=0;r<4;r++){
          float sa = fmaf(sca[kt][r], SCALE2, cb);
          float sb = fmaf(scb[kt][r], SCALE2, cb);
          sca[kt][r] = (mk4[r] != 0.f) ? sa : NEGBIG;
          scb[kt][r] = (mk4[r] != 0.f) ? sb : NEGBIG;
        }
      }
    } else {
      const int dba = delta + 63 - (wt*32 + fr);       // frag A base
      #pragma unroll
      for (int kt=0;kt<4;kt++){
        f32x4 mk4 = *reinterpret_cast<const f32x4*>(&maskf[team][buf][kt*16 + g*4]);
        #pragma unroll
        for (int r=0;r<4;r++){
          int da = dba + kt*16 + g*4 + r;
          int db = da - 16;
          da = da < 0 ? 0 : (da > 126 ? 126 : da);
          db = db < 0 ? 0 : (db > 126 ? 126 : db);
          float sa = fmaf(sca[kt][r], SCALE2, rel_sh[da]);
          float sb = fmaf(scb[kt][r], SCALE2, rel_sh[db]);
          sca[kt][r] = (mk4[r] != 0.f) ? sa : NEGBIG;
          scb[kt][r] = (mk4[r] != 0.f) ? sb : NEGBIG;
        }
      }
    }

    // online softmax per frag: in-lane over 16 keys, xor16/xor32, defer-max
    {
      float tmax = sca[0][0];
      #pragma unroll
      for (int kt=0;kt<4;kt++)
        #pragma unroll
        for (int r=0;r<4;r++) tmax = fmaxf(tmax, sca[kt][r]);
      tmax = fmaxf(tmax, __shfl_xor(tmax, 16));
      tmax = fmaxf(tmax, __shfl_xor(tmax, 32));
      if (!__all(tmax <= mruna + 8.f)){
        const float mnew = fmaxf(mruna, tmax);
        const float corr = exp2f(mruna - mnew);
        lruna *= corr;
        #pragma unroll
        for (int dt=0;dt<4;dt++)
          #pragma unroll
          for (int r=0;r<4;r++) ctxa[dt][r] *= corr;
        mruna = mnew;
      }
      float psum = 0.f;
      #pragma unroll
      for (int kt=0;kt<4;kt++)
        #pragma unroll
        for (int r=0;r<4;r++){
          float p = exp2f(sca[kt][r] - mruna);
          sca[kt][r] = p;
          psum += p;
        }
      psum += __shfl_xor(psum, 16);
      psum += __shfl_xor(psum, 32);
      lruna += psum;
    }
    {
      float tmax = scb[0][0];
      #pragma unroll
      for (int kt=0;kt<4;kt++)
        #pragma unroll
        for (int r=0;r<4;r++) tmax = fmaxf(tmax, scb[kt][r]);
      tmax = fmaxf(tmax, __shfl_xor(tmax, 16));
      tmax = fmaxf(tmax, __shfl_xor(tmax, 32));
      if (!__all(tmax <= mrunb + 8.f)){
        const float mnew = fmaxf(mrunb, tmax);
        const float corr = exp2f(mrunb - mnew);
        lrunb *= corr;
        #pragma unroll
        for (int dt=0;dt<4;dt++)
          #pragma unroll
          for (int r=0;r<4;r++) ctxb[dt][r] *= corr;
        mrunb = mnew;
      }
      float psum = 0.f;
      #pragma unroll
      for (int kt=0;kt<4;kt++)
        #pragma unroll
        for (int r=0;r<4;r++){
          float p = exp2f(scb[kt][r] - mrunb);
          scb[kt][r] = p;
          psum += p;
        }
      psum += __shfl_xor(psum, 16);
      psum += __shfl_xor(psum, 32);
      lrunb += psum;
    }

    // PV: ctx^T[d][q] += V^T[d][k] * P^T[k][q]; V-frags shared by both frags
    const char* vsb = (const char*)&kvbuf[1][team][buf][0][0];
#if HAVE_MFMA16
    short4v paa[4], pab[4];
    #pragma unroll
    for (int kt=0;kt<4;kt++){
      union { short4v s; __hip_bfloat162 h[2]; } ua, ub;
      ua.h[0] = __float22bfloat162_rn(make_float2(sca[kt][0], sca[kt][1]));
      ua.h[1] = __float22bfloat162_rn(make_float2(sca[kt][2], sca[kt][3]));
      ub.h[0] = __float22bfloat162_rn(make_float2(scb[kt][0], scb[kt][1]));
      ub.h[1] = __float22bfloat162_rn(make_float2(scb[kt][2], scb[kt][3]));
      paa[kt] = ua.s; pab[kt] = ub.s;
    }
    #pragma unroll
    for (int dt=0;dt<4;dt++){
      const int dr = dt*16 + fr;
      const int dswz = dr & 7;
      #pragma unroll
      for (int kt=0;kt<4;kt++){
        const int voff = (((kt*2 + (g>>1)) ^ dswz) << 4) + ((g&1)*8);
        short4v va = *reinterpret_cast<const short4v*>(vsb + dr*128 + voff);
        ctxa[dt] = __builtin_amdgcn_mfma_f32_16x16x16bf16_1k(va, paa[kt], ctxa[dt], 0,0,0);
        ctxb[dt] = __builtin_amdgcn_mfma_f32_16x16x16bf16_1k(va, pab[kt], ctxb[dt], 0,0,0);
      }
    }
#else
    unsigned pka[4][2], pkb[4][2];
    #pragma unroll
    for (int kt=0;kt<4;kt++){
      union { unsigned u; __hip_bfloat162 h; } u0, u1;
      u0.h = __float22bfloat162_rn(make_float2(sca[kt][0], sca[kt][1]));
      u1.h = __float22bfloat162_rn(make_float2(sca[kt][2], sca[kt][3]));
      pka[kt][0] = u0.u; pka[kt][1] = u1.u;
      u0.h = __float22bfloat162_rn(make_float2(scb[kt][0], scb[kt][1]));
      u1.h = __float22bfloat162_rn(make_float2(scb[kt][2], scb[kt][3]));
      pkb[kt][0] = u0.u; pkb[kt][1] = u1.u;
    }
    #pragma unroll
    for (int f=0;f<2;f++){
      union { short8 s8; unsigned u[4]; } bfa, bfb;
      #pragma unroll
      for (int m=0;m<4;m++){
        const int srcl = ((g&1)*2 + (m>>1))*16 + fr;
        unsigned a0 = __shfl((int)pka[f*2+0][m&1], srcl);
        unsigned a1 = __shfl((int)pka[f*2+1][m&1], srcl);
        bfa.u[m] = (g >> 1) ? a1 : a0;
        unsigned b0 = __shfl((int)pkb[f*2+0][m&1], srcl);
        unsigned b1 = __shfl((int)pkb[f*2+1][m&1], srcl);
        bfb.u[m] = (g >> 1) ? b1 : b0;
      }
      #pragma unroll
      for (int dt=0;dt<4;dt++){
        const int dr = dt*16 + fr;
        const int vswz = (dr & 7) << 4;
        short8 va = *reinterpret_cast<const short8*>(
            vsb + dr*128 + ((g*16 + f*64) ^ vswz));
        ctxa[dt] = __builtin_amdgcn_mfma_f32_16x16x32_bf16(va, bfa.s8, ctxa[dt], 0,0,0);
        ctxb[dt] = __builtin_amdgcn_mfma_f32_16x16x32_bf16(va, bfb.s8, ctxb[dt], 0,0,0);
      }
    }
#endif

    __syncthreads();
    buf ^= 1;
  }

  // ---- merge the two teams' partial (m, l, ctx) via LDS ----
  // overlay: mctx[128][72] f32 (36.9 KB) on kvbuf
  float* mctx = (float*)&kvbuf[0][0][0][0][0];
  const int rowA = wt*32 + fr, rowB = rowA + 16;
  if (team == 1){
    #pragma unroll
    for (int dt=0;dt<4;dt++){
      *reinterpret_cast<f32x4*>(&mctx[rowA*72 + dt*16 + g*4]) = ctxa[dt];
      *reinterpret_cast<f32x4*>(&mctx[rowB*72 + dt*16 + g*4]) = ctxb[dt];
    }
    ml[rowA][0] = mruna; ml[rowA][1] = lruna;
    ml[rowB][0] = mrunb; ml[rowB][1] = lrunb;
  }
  __syncthreads();
  if (team == 0){
    // frag A
    {
      const float m1 = ml[rowA][0], l1 = ml[rowA][1];
      const float m  = fmaxf(mruna, m1);
      const float s0 = exp2f(mruna - m), s1 = exp2f(m1 - m);
      const float rl = 1.f / (lruna*s0 + l1*s1);
      #pragma unroll
      for (int dt=0;dt<4;dt++){
        f32x4 c1 = *reinterpret_cast<const f32x4*>(&mctx[rowA*72 + dt*16 + g*4]);
        short4v o;
        #pragma unroll
        for (int r=0;r<4;r++) o[r] = f2b((ctxa[dt][r]*s0 + c1[r]*s1) * rl);
        *reinterpret_cast<short4v*>(
            Ctx + (size_t)(b*SEQ + qa)*D_MODEL + h*D_KK + dt*16 + g*4) = o;
      }
    }
    // frag B
    {
      const float m1 = ml[rowB][0], l1 = ml[rowB][1];
      const float m  = fmaxf(mrunb, m1);
      const float s0 = exp2f(mrunb - m), s1 = exp2f(m1 - m);
      const float rl = 1.f / (lrunb*s0 + l1*s1);
      #pragma unroll
      for (int dt=0;dt<4;dt++){
        f32x4 c1 = *reinterpret_cast<const f32x4*>(&mctx[rowB*72 + dt*16 + g*4]);
        short4v o;
        #pragma unroll
        for (int r=0;r<4;r++) o[r] = f2b((ctxb[dt][r]*s0 + c1[r]*s1) * rl);
        *reinterpret_cast<short4v*>(
            Ctx + (size_t)(b*SEQ + qb)*D_MODEL + h*D_KK + dt*16 + g*4) = o;
      }
    }
  }
}

// ---------------- launch ----------------
extern "C" void kernel_launch(void* const* d_in, const int* in_sizes, int n_in,
                              void* d_out, int out_size, void* d_ws, size_t ws_size,
                              hipStream_t stream) {
  const float* x    = (const float*)d_in[0];
  const int*   mask = (const int*)  d_in[1];
  const float* wq   = (const float*)d_in[2];
  const float* bq   = (const float*)d_in[3];
  const float* wk   = (const float*)d_in[4];
  const float* bk   = (const float*)d_in[5];
  const float* wv   = (const float*)d_in[6];
  const float* bv   = (const float*)d_in[7];
  const float* wo   = (const float*)d_in[8];
  const float* bo   = (const float*)d_in[9];
  const float* rel  = (const float*)d_in[10];

  const size_t NX = (size_t)NTOK * D_MODEL;      // 4194304
  const size_t NW = (size_t)D_MODEL * D_MODEL;   // 1048576
  if (ws_size < (NX + 4*NW + 4*NX) * sizeof(short)) return;
  short* xb   = (short*)d_ws;
  short* wqb  = xb  + NX;
  short* wkb  = wqb + NW;
  short* wvb  = wkb + NW;
  short* wob  = wvb + NW;
  short* Qb   = wob + NW;
  short* Kb   = Qb  + NX;
  short* Vtg  = Kb  + NX;   // V transposed per head: [B*H][64][SEQ]
  short* Ctxb = Vtg + NX;

  cvt_all_kernel<<<8192, 256, 0, stream>>>(x, wq, wk, wv, wo, xb);

  qkv_gemm_kernel<<<dim3(8, 32, 3), 256, 0, stream>>>(
      xb, wqb, wkb, wvb, bq, bk, bv, Qb, Kb, Vtg);

  attn_kernel<<<512, 512, 0, stream>>>(Qb, Kb, Vtg, mask, rel, Ctxb);

  out_gemm_kernel<<<dim3(16, 32), 256, 0, stream>>>(Ctxb, wob, bo, (float*)d_out);
}

// Round 6
// 128.804 us; speedup vs baseline: 1.1580x; 1.1580x over previous
//
#include <hip/hip_runtime.h>
#include <hip/hip_bf16.h>

typedef __attribute__((ext_vector_type(8))) short short8;
typedef __attribute__((ext_vector_type(4))) short short4v;
typedef __attribute__((ext_vector_type(4))) float f32x4;

#define D_MODEL 1024
#define N_HEADS 16
#define D_KK 64
#define BATCH 4
#define SEQ 1024
#define NTOK (BATCH*SEQ)

#define LOG2E  1.44269504f
#define SCALE2 (0.125f * 1.44269504f)
#define NEGBIG (-1.44269504e9f)

#if __has_builtin(__builtin_amdgcn_mfma_f32_16x16x16bf16_1k)
#define HAVE_MFMA16 1
#else
#define HAVE_MFMA16 0
#endif

// round-to-nearest-even f32 -> bf16 (bit pattern in short)
__device__ __forceinline__ short f2b(float f){
  unsigned u = __float_as_uint(f);
  u += 0x7fffu + ((u >> 16) & 1u);
  return (short)(u >> 16);
}

__device__ __forceinline__ void gl2lds16(const void* g, void* l){
  __builtin_amdgcn_global_load_lds(
      (const __attribute__((address_space(1))) void*)g,
      (__attribute__((address_space(3))) void*)l, 16, 0, 0);
}

// ---------------- fused f32 -> bf16 conversion (x, wq, wk, wv, wo) ----------
__global__ __launch_bounds__(256) void cvt_all_kernel(
    const float* __restrict__ x,  const float* __restrict__ wq,
    const float* __restrict__ wk, const float* __restrict__ wv,
    const float* __restrict__ wo, short* __restrict__ dst)
{
  const size_t NX = (size_t)NTOK * D_MODEL;
  const size_t NW = (size_t)D_MODEL * D_MODEL;
  size_t e = ((size_t)blockIdx.x * 256 + threadIdx.x) * 4;
  const float* s;
  size_t off;
  if      (e < NX)        { s = x;  off = e; }
  else if (e < NX +   NW) { s = wq; off = e - NX; }
  else if (e < NX + 2*NW) { s = wk; off = e - NX -   NW; }
  else if (e < NX + 3*NW) { s = wv; off = e - NX - 2*NW; }
  else                    { s = wo; off = e - NX - 3*NW; }
  f32x4 v = *reinterpret_cast<const f32x4*>(s + off);
  short4v o;
  o[0]=f2b(v[0]); o[1]=f2b(v[1]); o[2]=f2b(v[2]); o[3]=f2b(v[3]);
  *reinterpret_cast<short4v*>(dst + e) = o;
}

// ---------------- GEMM: C[M,N] = A[M,K] @ W[N,K]^T + bias ----------------
// 128xBN tile, BK=64, XOR-swizzled LDS (conflict-free b128 reads), 4 waves.
template<int BN, int MODE>
__device__ __forceinline__ void gemm_bt_body(const short* __restrict__ A,
    const short* __restrict__ W, const float* __restrict__ bias,
    void* __restrict__ Cout, int N, int K)
{
  constexpr int NF = BN / 32;
  __shared__ short As[128][64];
  __shared__ short Bs[BN][64];
  const int tid = threadIdx.x, lane = tid & 63, w = tid >> 6;
  const int wr = w >> 1, wc = w & 1;
  const int bn0 = blockIdx.x * BN, bm0 = blockIdx.y * 128;
  const int srow = lane >> 3;
  const int scol = ((lane & 7) ^ srow) * 8;
  const int fr = lane & 15, g = lane >> 4;

  f32x4 acc[4][NF];
  #pragma unroll
  for (int m=0;m<4;m++)
    #pragma unroll
    for (int n=0;n<NF;n++) acc[m][n] = (f32x4){0.f,0.f,0.f,0.f};

  for (int k0 = 0; k0 < K; k0 += 64){
    __syncthreads();
    #pragma unroll
    for (int i=0;i<4;i++){
      const int c = w*4 + i;
      gl2lds16(A + (size_t)(bm0 + c*8 + srow)*K + k0 + scol, &As[c*8][0]);
    }
    #pragma unroll
    for (int i=0;i<NF;i++){
      const int c = w*NF + i;
      gl2lds16(W + (size_t)(bn0 + c*8 + srow)*K + k0 + scol, &Bs[c*8][0]);
    }
    __syncthreads();
    #pragma unroll
    for (int f=0; f<2; f++){
      short8 af[4], bfr[NF];
      #pragma unroll
      for (int m=0;m<4;m++){
        const int rr = wr*64 + m*16 + fr;
        af[m] = *reinterpret_cast<const short8*>(
            (const char*)&As[0][0] + rr*128 + ((g*16 + f*64) ^ ((rr&7)<<4)));
      }
      #pragma unroll
      for (int n=0;n<NF;n++){
        const int rr = wc*(BN/2) + n*16 + fr;
        bfr[n] = *reinterpret_cast<const short8*>(
            (const char*)&Bs[0][0] + rr*128 + ((g*16 + f*64) ^ ((rr&7)<<4)));
      }
      #pragma unroll
      for (int m=0;m<4;m++)
        #pragma unroll
        for (int n=0;n<NF;n++)
          acc[m][n] = __builtin_amdgcn_mfma_f32_16x16x32_bf16(af[m], bfr[n], acc[m][n], 0,0,0);
    }
  }

  #pragma unroll
  for (int n=0;n<NF;n++){
    const int col = bn0 + wc*(BN/2) + n*16 + fr;
    const float bv = bias[col];
    if (MODE == 2){
      const int hh = col >> 6, dd = col & 63;
      #pragma unroll
      for (int m=0;m<4;m++){
        const int row0 = bm0 + wr*64 + m*16 + g*4;
        const int bb = row0 >> 10, ss = row0 & 1023;
        short4v o;
        #pragma unroll
        for (int r=0;r<4;r++) o[r] = f2b(acc[m][n][r] + bv);
        *reinterpret_cast<short4v*>(
            (short*)Cout + ((size_t)(bb*N_HEADS+hh)*D_KK + dd)*SEQ + ss) = o;
      }
    } else {
      #pragma unroll
      for (int m=0;m<4;m++){
        const int row0 = bm0 + wr*64 + m*16 + g*4;
        #pragma unroll
        for (int r=0;r<4;r++){
          float v = acc[m][n][r] + bv;
          if (MODE == 1) ((float*)Cout)[(size_t)(row0+r)*N + col] = v;
          else           ((short*)Cout)[(size_t)(row0+r)*N + col] = f2b(v);
        }
      }
    }
  }
}

__global__ __launch_bounds__(256) void qkv_gemm_kernel(
    const short* __restrict__ X,
    const short* __restrict__ Wq, const short* __restrict__ Wk, const short* __restrict__ Wv,
    const float* __restrict__ bq, const float* __restrict__ bk, const float* __restrict__ bv,
    short* __restrict__ Q, short* __restrict__ K, short* __restrict__ V)
{
  const int z = blockIdx.z;
  if (z == 0)      gemm_bt_body<128,0>(X, Wq, bq, Q, D_MODEL, D_MODEL);
  else if (z == 1) gemm_bt_body<128,0>(X, Wk, bk, K, D_MODEL, D_MODEL);
  else             gemm_bt_body<128,2>(X, Wv, bv, V, D_MODEL, D_MODEL);
}

__global__ __launch_bounds__(256) void out_gemm_kernel(
    const short* __restrict__ Ctx, const short* __restrict__ Wo,
    const float* __restrict__ bo, float* __restrict__ Out)
{
  gemm_bt_body<64,1>(Ctx, Wo, bo, Out, D_MODEL, D_MODEL);
}

// ---------------- flash attention, swapped-operand, KV-split teams ---------
// 512 blocks x 512 threads (8 waves = 2 teams of 4). Team 0: keys [0,512),
// team 1: keys [512,1024), same 128 q-rows; merge (m,l,ctx) via LDS at end.
// launch_bounds(512,2): cap 256 regs — (512,4)'s 128-cap caused 80MB of
// scratch spill traffic in round 5.
__global__ __launch_bounds__(512, 2) void attn_kernel(
    const short* __restrict__ Qb, const short* __restrict__ Kb,
    const short* __restrict__ Vtg, const int* __restrict__ mask,
    const float* __restrict__ rel_table, short* __restrict__ Ctx)
{
  const int bid = blockIdx.x;
  const int xcd = bid & 7, slot = bid >> 3;
  const int bh = xcd * 8 + (slot >> 3);      // 8 (b,h) groups per XCD
  const int qt = slot & 7;                   // 8 q-tiles of 128 rows
  const int b = bh >> 4, h = bh & 15;
  const int q0 = qt * 128;
  const int tid = threadIdx.x, lane = tid & 63, w = tid >> 6;
  const int team = w >> 2, wt = w & 3;
  const int fr = lane & 15, g = lane >> 4;

  __shared__ short kvbuf[2][2][2][64][64];  // [K/V][team][buf][row][64], swizzled
  __shared__ float rel_sh[128];
  __shared__ float maskf[2][2][64];
  __shared__ float ml[128][2];

  for (int i = tid; i < 127; i += 512) rel_sh[i] = rel_table[i * N_HEADS + h] * LOG2E;
  const float cb_lo = rel_table[0*N_HEADS + h]   * LOG2E;
  const float cb_hi = rel_table[126*N_HEADS + h] * LOG2E;

  const short* Qg = Qb + (size_t)b*SEQ*D_MODEL + h*D_KK;
  const short* Kg = Kb + (size_t)b*SEQ*D_MODEL + h*D_KK;
  const short* Vg = Vtg + (size_t)bh*D_KK*SEQ;

  const int qa = q0 + wt*32 + fr;
  const int qb = qa + 16;
  short8 qfa[2], qfb[2];
  #pragma unroll
  for (int f=0; f<2; f++){
    qfa[f] = *reinterpret_cast<const short8*>(Qg + (size_t)qa*D_MODEL + g*8 + f*32);
    qfb[f] = *reinterpret_cast<const short8*>(Qg + (size_t)qb*D_MODEL + g*8 + f*32);
  }

  f32x4 ctxa[4], ctxb[4];
  #pragma unroll
  for (int dt=0; dt<4; dt++){ ctxa[dt] = (f32x4){0.f,0.f,0.f,0.f}; ctxb[dt] = ctxa[dt]; }
  float mruna = -3.0e38f, lruna = 0.f, mrunb = -3.0e38f, lrunb = 0.f;

  const int srow = lane >> 3;
  const int scol = ((lane & 7) ^ srow) * 8;
  auto stage = [&](int buf, int kv0){
    #pragma unroll
    for (int i=0;i<2;i++){
      const int c = wt*2 + i;
      gl2lds16(Kg + (size_t)(kv0 + c*8 + srow)*D_MODEL + scol, &kvbuf[0][team][buf][c*8][0]);
      gl2lds16(Vg + (size_t)(c*8 + srow)*SEQ + kv0 + scol,     &kvbuf[1][team][buf][c*8][0]);
    }
    if (wt == 0)
      maskf[team][buf][lane] = mask[b*SEQ + kv0 + lane] ? 1.f : 0.f;
  };

  const int kvbase = team * 512;
  stage(0, kvbase);
  __syncthreads();

  int buf = 0;
  for (int t = 0; t < 8; ++t){
    const int kv0 = kvbase + t * 64;
    if (t < 7) stage(buf ^ 1, kv0 + 64);

    // QK^T swapped: sc = K-tile · Q^T -> S^T[key][q], two q-frags share kf
    const char* ksb = (const char*)&kvbuf[0][team][buf][0][0];
    f32x4 sca[4], scb[4];
    #pragma unroll
    for (int kt=0;kt<4;kt++){
      sca[kt] = (f32x4){0.f,0.f,0.f,0.f};
      scb[kt] = (f32x4){0.f,0.f,0.f,0.f};
      const int rr = kt*16 + fr;
      const int swz = (rr & 7) << 4;
      #pragma unroll
      for (int f=0;f<2;f++){
        short8 kf = *reinterpret_cast<const short8*>(
            ksb + rr*128 + ((g*16 + f*64) ^ swz));
        sca[kt] = __builtin_amdgcn_mfma_f32_16x16x32_bf16(kf, qfa[f], sca[kt], 0,0,0);
        scb[kt] = __builtin_amdgcn_mfma_f32_16x16x32_bf16(kf, qfb[f], scb[kt], 0,0,0);
      }
    }

    // scale + bias + mask (log2 domain)
    const int delta = kv0 - q0;
    if (delta <= -128 || delta >= 192){
      const float cb = (delta > 0) ? cb_hi : cb_lo;
      #pragma unroll
      for (int kt=0;kt<4;kt++){
        f32x4 mk4 = *reinterpret_cast<const f32x4*>(&maskf[team][buf][kt*16 + g*4]);
        #pragma unroll
        for (int r=0;r<4;r++){
          float sa = fmaf(sca[kt][r], SCALE2, cb);
          float sb = fmaf(scb[kt][r], SCALE2, cb);
          sca[kt][r] = (mk4[r] != 0.f) ? sa : NEGBIG;
          scb[kt][r] = (mk4[r] != 0.f) ? sb : NEGBIG;
        }
      }
    } else {
      const int dba = delta + 63 - (wt*32 + fr);
      #pragma unroll
      for (int kt=0;kt<4;kt++){
        f32x4 mk4 = *reinterpret_cast<const f32x4*>(&maskf[team][buf][kt*16 + g*4]);
        #pragma unroll
        for (int r=0;r<4;r++){
          int da = dba + kt*16 + g*4 + r;
          int db = da - 16;
          da = da < 0 ? 0 : (da > 126 ? 126 : da);
          db = db < 0 ? 0 : (db > 126 ? 126 : db);
          float sa = fmaf(sca[kt][r], SCALE2, rel_sh[da]);
          float sb = fmaf(scb[kt][r], SCALE2, rel_sh[db]);
          sca[kt][r] = (mk4[r] != 0.f) ? sa : NEGBIG;
          scb[kt][r] = (mk4[r] != 0.f) ? sb : NEGBIG;
        }
      }
    }

    // softmax+pack per frag: exp output packed straight to bf16 (short live
    // ranges — f32 scores die here, only 4 packed regs survive per frag)
    short4v paa[4], pab[4];
    {
      float tmax = sca[0][0];
      #pragma unroll
      for (int kt=0;kt<4;kt++)
        #pragma unroll
        for (int r=0;r<4;r++) tmax = fmaxf(tmax, sca[kt][r]);
      tmax = fmaxf(tmax, __shfl_xor(tmax, 16));
      tmax = fmaxf(tmax, __shfl_xor(tmax, 32));
      if (!__all(tmax <= mruna + 8.f)){
        const float mnew = fmaxf(mruna, tmax);
        const float corr = exp2f(mruna - mnew);
        lruna *= corr;
        #pragma unroll
        for (int dt=0;dt<4;dt++)
          #pragma unroll
          for (int r=0;r<4;r++) ctxa[dt][r] *= corr;
        mruna = mnew;
      }
      float psum = 0.f;
      #pragma unroll
      for (int kt=0;kt<4;kt++){
        float p0 = exp2f(sca[kt][0] - mruna);
        float p1 = exp2f(sca[kt][1] - mruna);
        float p2 = exp2f(sca[kt][2] - mruna);
        float p3 = exp2f(sca[kt][3] - mruna);
        psum += (p0 + p1) + (p2 + p3);
        union { short4v s; __hip_bfloat162 h[2]; } u;
        u.h[0] = __float22bfloat162_rn(make_float2(p0, p1));
        u.h[1] = __float22bfloat162_rn(make_float2(p2, p3));
        paa[kt] = u.s;
      }
      psum += __shfl_xor(psum, 16);
      psum += __shfl_xor(psum, 32);
      lruna += psum;
    }
    {
      float tmax = scb[0][0];
      #pragma unroll
      for (int kt=0;kt<4;kt++)
        #pragma unroll
        for (int r=0;r<4;r++) tmax = fmaxf(tmax, scb[kt][r]);
      tmax = fmaxf(tmax, __shfl_xor(tmax, 16));
      tmax = fmaxf(tmax, __shfl_xor(tmax, 32));
      if (!__all(tmax <= mrunb + 8.f)){
        const float mnew = fmaxf(mrunb, tmax);
        const float corr = exp2f(mrunb - mnew);
        lrunb *= corr;
        #pragma unroll
        for (int dt=0;dt<4;dt++)
          #pragma unroll
          for (int r=0;r<4;r++) ctxb[dt][r] *= corr;
        mrunb = mnew;
      }
      float psum = 0.f;
      #pragma unroll
      for (int kt=0;kt<4;kt++){
        float p0 = exp2f(scb[kt][0] - mrunb);
        float p1 = exp2f(scb[kt][1] - mrunb);
        float p2 = exp2f(scb[kt][2] - mrunb);
        float p3 = exp2f(scb[kt][3] - mrunb);
        psum += (p0 + p1) + (p2 + p3);
        union { short4v s; __hip_bfloat162 h[2]; } u;
        u.h[0] = __float22bfloat162_rn(make_float2(p0, p1));
        u.h[1] = __float22bfloat162_rn(make_float2(p2, p3));
        pab[kt] = u.s;
      }
      psum += __shfl_xor(psum, 16);
      psum += __shfl_xor(psum, 32);
      lrunb += psum;
    }

    // PV: ctx^T[d][q] += V^T[d][k] * P^T[k][q]; V-frags shared by both frags
    const char* vsb = (const char*)&kvbuf[1][team][buf][0][0];
#if HAVE_MFMA16
    #pragma unroll
    for (int dt=0;dt<4;dt++){
      const int dr = dt*16 + fr;
      const int dswz = dr & 7;
      #pragma unroll
      for (int kt=0;kt<4;kt++){
        const int voff = (((kt*2 + (g>>1)) ^ dswz) << 4) + ((g&1)*8);
        short4v va = *reinterpret_cast<const short4v*>(vsb + dr*128 + voff);
        ctxa[dt] = __builtin_amdgcn_mfma_f32_16x16x16bf16_1k(va, paa[kt], ctxa[dt], 0,0,0);
        ctxb[dt] = __builtin_amdgcn_mfma_f32_16x16x16bf16_1k(va, pab[kt], ctxb[dt], 0,0,0);
      }
    }
#else
    #pragma unroll
    for (int f=0;f<2;f++){
      union { short8 s8; unsigned u[4]; } bfa, bfb;
      #pragma unroll
      for (int m=0;m<4;m++){
        const int srcl = ((g&1)*2 + (m>>1))*16 + fr;
        union { short4v s; unsigned u[2]; } ca0, ca1, cb0, cb1;
        ca0.s = paa[f*2+0]; ca1.s = paa[f*2+1];
        cb0.s = pab[f*2+0]; cb1.s = pab[f*2+1];
        unsigned a0 = __shfl((int)ca0.u[m&1], srcl);
        unsigned a1 = __shfl((int)ca1.u[m&1], srcl);
        bfa.u[m] = (g >> 1) ? a1 : a0;
        unsigned b0 = __shfl((int)cb0.u[m&1], srcl);
        unsigned b1 = __shfl((int)cb1.u[m&1], srcl);
        bfb.u[m] = (g >> 1) ? b1 : b0;
      }
      #pragma unroll
      for (int dt=0;dt<4;dt++){
        const int dr = dt*16 + fr;
        const int vswz = (dr & 7) << 4;
        short8 va = *reinterpret_cast<const short8*>(
            vsb + dr*128 + ((g*16 + f*64) ^ vswz));
        ctxa[dt] = __builtin_amdgcn_mfma_f32_16x16x32_bf16(va, bfa.s8, ctxa[dt], 0,0,0);
        ctxb[dt] = __builtin_amdgcn_mfma_f32_16x16x32_bf16(va, bfb.s8, ctxb[dt], 0,0,0);
      }
    }
#endif

    __syncthreads();
    buf ^= 1;
  }

  // ---- merge the two teams' partial (m, l, ctx) via LDS ----
  float* mctx = (float*)&kvbuf[0][0][0][0][0];
  const int rowA = wt*32 + fr, rowB = rowA + 16;
  if (team == 1){
    #pragma unroll
    for (int dt=0;dt<4;dt++){
      *reinterpret_cast<f32x4*>(&mctx[rowA*72 + dt*16 + g*4]) = ctxa[dt];
      *reinterpret_cast<f32x4*>(&mctx[rowB*72 + dt*16 + g*4]) = ctxb[dt];
    }
    ml[rowA][0] = mruna; ml[rowA][1] = lruna;
    ml[rowB][0] = mrunb; ml[rowB][1] = lrunb;
  }
  __syncthreads();
  if (team == 0){
    {
      const float m1 = ml[rowA][0], l1 = ml[rowA][1];
      const float m  = fmaxf(mruna, m1);
      const float s0 = exp2f(mruna - m), s1 = exp2f(m1 - m);
      const float rl = 1.f / (lruna*s0 + l1*s1);
      #pragma unroll
      for (int dt=0;dt<4;dt++){
        f32x4 c1 = *reinterpret_cast<const f32x4*>(&mctx[rowA*72 + dt*16 + g*4]);
        short4v o;
        #pragma unroll
        for (int r=0;r<4;r++) o[r] = f2b((ctxa[dt][r]*s0 + c1[r]*s1) * rl);
        *reinterpret_cast<short4v*>(
            Ctx + (size_t)(b*SEQ + qa)*D_MODEL + h*D_KK + dt*16 + g*4) = o;
      }
    }
    {
      const float m1 = ml[rowB][0], l1 = ml[rowB][1];
      const float m  = fmaxf(mrunb, m1);
      const float s0 = exp2f(mrunb - m), s1 = exp2f(m1 - m);
      const float rl = 1.f / (lrunb*s0 + l1*s1);
      #pragma unroll
      for (int dt=0;dt<4;dt++){
        f32x4 c1 = *reinterpret_cast<const f32x4*>(&mctx[rowB*72 + dt*16 + g*4]);
        short4v o;
        #pragma unroll
        for (int r=0;r<4;r++) o[r] = f2b((ctxb[dt][r]*s0 + c1[r]*s1) * rl);
        *reinterpret_cast<short4v*>(
            Ctx + (size_t)(b*SEQ + qb)*D_MODEL + h*D_KK + dt*16 + g*4) = o;
      }
    }
  }
}

// ---------------- launch ----------------
extern "C" void kernel_launch(void* const* d_in, const int* in_sizes, int n_in,
                              void* d_out, int out_size, void* d_ws, size_t ws_size,
                              hipStream_t stream) {
  const float* x    = (const float*)d_in[0];
  const int*   mask = (const int*)  d_in[1];
  const float* wq   = (const float*)d_in[2];
  const float* bq   = (const float*)d_in[3];
  const float* wk   = (const float*)d_in[4];
  const float* bk   = (const float*)d_in[5];
  const float* wv   = (const float*)d_in[6];
  const float* bv   = (const float*)d_in[7];
  const float* wo   = (const float*)d_in[8];
  const float* bo   = (const float*)d_in[9];
  const float* rel  = (const float*)d_in[10];

  const size_t NX = (size_t)NTOK * D_MODEL;      // 4194304
  const size_t NW = (size_t)D_MODEL * D_MODEL;   // 1048576
  if (ws_size < (NX + 4*NW + 4*NX) * sizeof(short)) return;
  short* xb   = (short*)d_ws;
  short* wqb  = xb  + NX;
  short* wkb  = wqb + NW;
  short* wvb  = wkb + NW;
  short* wob  = wvb + NW;
  short* Qb   = wob + NW;
  short* Kb   = Qb  + NX;
  short* Vtg  = Kb  + NX;   // V transposed per head: [B*H][64][SEQ]
  short* Ctxb = Vtg + NX;

  cvt_all_kernel<<<8192, 256, 0, stream>>>(x, wq, wk, wv, wo, xb);

  qkv_gemm_kernel<<<dim3(8, 32, 3), 256, 0, stream>>>(
      xb, wqb, wkb, wvb, bq, bk, bv, Qb, Kb, Vtg);

  attn_kernel<<<512, 512, 0, stream>>>(Qb, Kb, Vtg, mask, rel, Ctxb);

  out_gemm_kernel<<<dim3(16, 32), 256, 0, stream>>>(Ctxb, wob, bo, (float*)d_out);
}

// Round 7
// 124.987 us; speedup vs baseline: 1.1933x; 1.0305x over previous
//
#include <hip/hip_runtime.h>
#include <hip/hip_bf16.h>

typedef __attribute__((ext_vector_type(8))) short short8;
typedef __attribute__((ext_vector_type(4))) short short4v;
typedef __attribute__((ext_vector_type(4))) float f32x4;

#define D_MODEL 1024
#define N_HEADS 16
#define D_KK 64
#define BATCH 4
#define SEQ 1024
#define NTOK (BATCH*SEQ)

#define LOG2E  1.44269504f
#define SCALE2 (0.125f * 1.44269504f)
#define NEGBIG (-1.44269504e9f)

#if __has_builtin(__builtin_amdgcn_mfma_f32_16x16x16bf16_1k)
#define HAVE_MFMA16 1
#else
#define HAVE_MFMA16 0
#endif

// round-to-nearest-even f32 -> bf16 (bit pattern in short)
__device__ __forceinline__ short f2b(float f){
  unsigned u = __float_as_uint(f);
  u += 0x7fffu + ((u >> 16) & 1u);
  return (short)(u >> 16);
}

__device__ __forceinline__ void gl2lds16(const void* g, void* l){
  __builtin_amdgcn_global_load_lds(
      (const __attribute__((address_space(1))) void*)g,
      (__attribute__((address_space(3))) void*)l, 16, 0, 0);
}

// ---------------- fused f32 -> bf16 conversion (x, wq, wk, wv, wo) ----------
__global__ __launch_bounds__(256) void cvt_all_kernel(
    const float* __restrict__ x,  const float* __restrict__ wq,
    const float* __restrict__ wk, const float* __restrict__ wv,
    const float* __restrict__ wo, short* __restrict__ dst)
{
  const size_t NX = (size_t)NTOK * D_MODEL;
  const size_t NW = (size_t)D_MODEL * D_MODEL;
  size_t e = ((size_t)blockIdx.x * 256 + threadIdx.x) * 4;
  const float* s;
  size_t off;
  if      (e < NX)        { s = x;  off = e; }
  else if (e < NX +   NW) { s = wq; off = e - NX; }
  else if (e < NX + 2*NW) { s = wk; off = e - NX -   NW; }
  else if (e < NX + 3*NW) { s = wv; off = e - NX - 2*NW; }
  else                    { s = wo; off = e - NX - 3*NW; }
  f32x4 v = *reinterpret_cast<const f32x4*>(s + off);
  short4v o;
  o[0]=f2b(v[0]); o[1]=f2b(v[1]); o[2]=f2b(v[2]); o[3]=f2b(v[3]);
  *reinterpret_cast<short4v*>(dst + e) = o;
}

// ---------------- GEMM: C[M,N] = A[M,K] @ W[N,K]^T + bias ----------------
// 128xBN tile, BK=64, XOR-swizzled LDS (conflict-free b128 reads), 4 waves.
template<int BN, int MODE>
__device__ __forceinline__ void gemm_bt_body(const short* __restrict__ A,
    const short* __restrict__ W, const float* __restrict__ bias,
    void* __restrict__ Cout, int N, int K)
{
  constexpr int NF = BN / 32;
  __shared__ short As[128][64];
  __shared__ short Bs[BN][64];
  const int tid = threadIdx.x, lane = tid & 63, w = tid >> 6;
  const int wr = w >> 1, wc = w & 1;
  const int bn0 = blockIdx.x * BN, bm0 = blockIdx.y * 128;
  const int srow = lane >> 3;
  const int scol = ((lane & 7) ^ srow) * 8;
  const int fr = lane & 15, g = lane >> 4;

  f32x4 acc[4][NF];
  #pragma unroll
  for (int m=0;m<4;m++)
    #pragma unroll
    for (int n=0;n<NF;n++) acc[m][n] = (f32x4){0.f,0.f,0.f,0.f};

  for (int k0 = 0; k0 < K; k0 += 64){
    __syncthreads();
    #pragma unroll
    for (int i=0;i<4;i++){
      const int c = w*4 + i;
      gl2lds16(A + (size_t)(bm0 + c*8 + srow)*K + k0 + scol, &As[c*8][0]);
    }
    #pragma unroll
    for (int i=0;i<NF;i++){
      const int c = w*NF + i;
      gl2lds16(W + (size_t)(bn0 + c*8 + srow)*K + k0 + scol, &Bs[c*8][0]);
    }
    __syncthreads();
    #pragma unroll
    for (int f=0; f<2; f++){
      short8 af[4], bfr[NF];
      #pragma unroll
      for (int m=0;m<4;m++){
        const int rr = wr*64 + m*16 + fr;
        af[m] = *reinterpret_cast<const short8*>(
            (const char*)&As[0][0] + rr*128 + ((g*16 + f*64) ^ ((rr&7)<<4)));
      }
      #pragma unroll
      for (int n=0;n<NF;n++){
        const int rr = wc*(BN/2) + n*16 + fr;
        bfr[n] = *reinterpret_cast<const short8*>(
            (const char*)&Bs[0][0] + rr*128 + ((g*16 + f*64) ^ ((rr&7)<<4)));
      }
      #pragma unroll
      for (int m=0;m<4;m++)
        #pragma unroll
        for (int n=0;n<NF;n++)
          acc[m][n] = __builtin_amdgcn_mfma_f32_16x16x32_bf16(af[m], bfr[n], acc[m][n], 0,0,0);
    }
  }

  #pragma unroll
  for (int n=0;n<NF;n++){
    const int col = bn0 + wc*(BN/2) + n*16 + fr;
    const float bv = bias[col];
    if (MODE == 2){
      const int hh = col >> 6, dd = col & 63;
      #pragma unroll
      for (int m=0;m<4;m++){
        const int row0 = bm0 + wr*64 + m*16 + g*4;
        const int bb = row0 >> 10, ss = row0 & 1023;
        short4v o;
        #pragma unroll
        for (int r=0;r<4;r++) o[r] = f2b(acc[m][n][r] + bv);
        *reinterpret_cast<short4v*>(
            (short*)Cout + ((size_t)(bb*N_HEADS+hh)*D_KK + dd)*SEQ + ss) = o;
      }
    } else {
      #pragma unroll
      for (int m=0;m<4;m++){
        const int row0 = bm0 + wr*64 + m*16 + g*4;
        #pragma unroll
        for (int r=0;r<4;r++){
          float v = acc[m][n][r] + bv;
          if (MODE == 1) ((float*)Cout)[(size_t)(row0+r)*N + col] = v;
          else           ((short*)Cout)[(size_t)(row0+r)*N + col] = f2b(v);
        }
      }
    }
  }
}

__global__ __launch_bounds__(256) void qkv_gemm_kernel(
    const short* __restrict__ X,
    const short* __restrict__ Wq, const short* __restrict__ Wk, const short* __restrict__ Wv,
    const float* __restrict__ bq, const float* __restrict__ bk, const float* __restrict__ bv,
    short* __restrict__ Q, short* __restrict__ K, short* __restrict__ V)
{
  const int z = blockIdx.z;
  if (z == 0)      gemm_bt_body<128,0>(X, Wq, bq, Q, D_MODEL, D_MODEL);
  else if (z == 1) gemm_bt_body<128,0>(X, Wk, bk, K, D_MODEL, D_MODEL);
  else             gemm_bt_body<128,2>(X, Wv, bv, V, D_MODEL, D_MODEL);
}

__global__ __launch_bounds__(256) void out_gemm_kernel(
    const short* __restrict__ Ctx, const short* __restrict__ Wo,
    const float* __restrict__ bo, float* __restrict__ Out)
{
  gemm_bt_body<64,1>(Ctx, Wo, bo, Out, D_MODEL, D_MODEL);
}

// ---------------- flash attention, swapped-operand, KV-split teams ---------
// 512 blocks x 512 threads (8 waves = 2 teams of 4). Team 0: keys [0,512),
// team 1: keys [512,1024); merge (m,l,ctx) via LDS at end.
// Softmax: per-lane partial lrun (epilogue reduce); cross-lane max only in
// the rare defer-max rescale branch; mask folded into additive per-key bias
// computed at stage time (far tiles: 1 fma/score).
__global__ __launch_bounds__(512, 2) void attn_kernel(
    const short* __restrict__ Qb, const short* __restrict__ Kb,
    const short* __restrict__ Vtg, const int* __restrict__ mask,
    const float* __restrict__ rel_table, short* __restrict__ Ctx)
{
  const int bid = blockIdx.x;
  const int xcd = bid & 7, slot = bid >> 3;
  const int bh = xcd * 8 + (slot >> 3);      // 8 (b,h) groups per XCD
  const int qt = slot & 7;                   // 8 q-tiles of 128 rows
  const int b = bh >> 4, h = bh & 15;
  const int q0 = qt * 128;
  const int tid = threadIdx.x, lane = tid & 63, w = tid >> 6;
  const int team = w >> 2, wt = w & 3;
  const int fr = lane & 15, g = lane >> 4;

  __shared__ short kvbuf[2][2][2][64][64];  // [K/V][team][buf][row][64], swizzled
  __shared__ float rel_sh[128];
  __shared__ float mbias[2][2][64];         // additive bias: mask/clamped-rel folded
  __shared__ float ml[128][2];

  for (int i = tid; i < 127; i += 512) rel_sh[i] = rel_table[i * N_HEADS + h] * LOG2E;
  const float cb_lo = rel_table[0*N_HEADS + h]   * LOG2E;
  const float cb_hi = rel_table[126*N_HEADS + h] * LOG2E;

  const short* Qg = Qb + (size_t)b*SEQ*D_MODEL + h*D_KK;
  const short* Kg = Kb + (size_t)b*SEQ*D_MODEL + h*D_KK;
  const short* Vg = Vtg + (size_t)bh*D_KK*SEQ;

  const int qa = q0 + wt*32 + fr;
  const int qb = qa + 16;
  short8 qfa[2], qfb[2];
  #pragma unroll
  for (int f=0; f<2; f++){
    qfa[f] = *reinterpret_cast<const short8*>(Qg + (size_t)qa*D_MODEL + g*8 + f*32);
    qfb[f] = *reinterpret_cast<const short8*>(Qg + (size_t)qb*D_MODEL + g*8 + f*32);
  }

  f32x4 ctxa[4], ctxb[4];
  #pragma unroll
  for (int dt=0; dt<4; dt++){ ctxa[dt] = (f32x4){0.f,0.f,0.f,0.f}; ctxb[dt] = ctxa[dt]; }
  float mruna = -3.0e38f, lruna = 0.f, mrunb = -3.0e38f, lrunb = 0.f;

  const int srow = lane >> 3;
  const int scol = ((lane & 7) ^ srow) * 8;
  auto stage = [&](int buf, int kv0){
    #pragma unroll
    for (int i=0;i<2;i++){
      const int c = wt*2 + i;
      gl2lds16(Kg + (size_t)(kv0 + c*8 + srow)*D_MODEL + scol, &kvbuf[0][team][buf][c*8][0]);
      gl2lds16(Vg + (size_t)(c*8 + srow)*SEQ + kv0 + scol,     &kvbuf[1][team][buf][c*8][0]);
    }
    if (wt == 0){
      const int delta = kv0 - q0;
      const bool far = (delta <= -128 || delta >= 192);
      const float cb = far ? (delta > 0 ? cb_hi : cb_lo) : 0.f;
      mbias[team][buf][lane] = mask[b*SEQ + kv0 + lane] ? cb : NEGBIG;
    }
  };

  const int kvbase = team * 512;
  stage(0, kvbase);
  __syncthreads();

  int buf = 0;
  for (int t = 0; t < 8; ++t){
    const int kv0 = kvbase + t * 64;
    if (t < 7) stage(buf ^ 1, kv0 + 64);

    // QK^T swapped: sc = K-tile · Q^T -> S^T[key][q], two q-frags share kf
    const char* ksb = (const char*)&kvbuf[0][team][buf][0][0];
    f32x4 sca[4], scb[4];
    __builtin_amdgcn_s_setprio(1);
    #pragma unroll
    for (int kt=0;kt<4;kt++){
      sca[kt] = (f32x4){0.f,0.f,0.f,0.f};
      scb[kt] = (f32x4){0.f,0.f,0.f,0.f};
      const int rr = kt*16 + fr;
      const int swz = (rr & 7) << 4;
      #pragma unroll
      for (int f=0;f<2;f++){
        short8 kf = *reinterpret_cast<const short8*>(
            ksb + rr*128 + ((g*16 + f*64) ^ swz));
        sca[kt] = __builtin_amdgcn_mfma_f32_16x16x32_bf16(kf, qfa[f], sca[kt], 0,0,0);
        scb[kt] = __builtin_amdgcn_mfma_f32_16x16x32_bf16(kf, qfb[f], scb[kt], 0,0,0);
      }
    }
    __builtin_amdgcn_s_setprio(0);

    // scale + folded bias (mask/clamped-rel already in mbias)
    const int delta = kv0 - q0;
    if (delta <= -128 || delta >= 192){
      #pragma unroll
      for (int kt=0;kt<4;kt++){
        f32x4 mb4 = *reinterpret_cast<const f32x4*>(&mbias[team][buf][kt*16 + g*4]);
        #pragma unroll
        for (int r=0;r<4;r++){
          sca[kt][r] = fmaf(sca[kt][r], SCALE2, mb4[r]);
          scb[kt][r] = fmaf(scb[kt][r], SCALE2, mb4[r]);
        }
      }
    } else {
      const int dba = delta + 63 - (wt*32 + fr);
      #pragma unroll
      for (int kt=0;kt<4;kt++){
        f32x4 mb4 = *reinterpret_cast<const f32x4*>(&mbias[team][buf][kt*16 + g*4]);
        #pragma unroll
        for (int r=0;r<4;r++){
          int da = dba + kt*16 + g*4 + r;
          int db = da - 16;
          da = da < 0 ? 0 : (da > 126 ? 126 : da);
          db = db < 0 ? 0 : (db > 126 ? 126 : db);
          sca[kt][r] = fmaf(sca[kt][r], SCALE2, rel_sh[da]) + mb4[r];
          scb[kt][r] = fmaf(scb[kt][r], SCALE2, rel_sh[db]) + mb4[r];
        }
      }
    }

    // softmax+pack per frag: in-lane fmax, cross-lane max only on rescale,
    // per-lane partial lrun (reduced once in epilogue)
    short4v paa[4], pab[4];
    {
      float tmax = sca[0][0];
      #pragma unroll
      for (int kt=0;kt<4;kt++)
        #pragma unroll
        for (int r=0;r<4;r++) tmax = fmaxf(tmax, sca[kt][r]);
      if (!__all(tmax <= mruna + 8.f)){
        float tm = fmaxf(tmax, __shfl_xor(tmax, 16));
        tm = fmaxf(tm, __shfl_xor(tm, 32));
        const float mnew = fmaxf(mruna, tm);
        const float corr = exp2f(mruna - mnew);
        lruna *= corr;
        #pragma unroll
        for (int dt=0;dt<4;dt++)
          #pragma unroll
          for (int r=0;r<4;r++) ctxa[dt][r] *= corr;
        mruna = mnew;
      }
      float psum = 0.f;
      #pragma unroll
      for (int kt=0;kt<4;kt++){
        float p0 = exp2f(sca[kt][0] - mruna);
        float p1 = exp2f(sca[kt][1] - mruna);
        float p2 = exp2f(sca[kt][2] - mruna);
        float p3 = exp2f(sca[kt][3] - mruna);
        psum += (p0 + p1) + (p2 + p3);
        union { short4v s; __hip_bfloat162 h[2]; } u;
        u.h[0] = __float22bfloat162_rn(make_float2(p0, p1));
        u.h[1] = __float22bfloat162_rn(make_float2(p2, p3));
        paa[kt] = u.s;
      }
      lruna += psum;
    }
    {
      float tmax = scb[0][0];
      #pragma unroll
      for (int kt=0;kt<4;kt++)
        #pragma unroll
        for (int r=0;r<4;r++) tmax = fmaxf(tmax, scb[kt][r]);
      if (!__all(tmax <= mrunb + 8.f)){
        float tm = fmaxf(tmax, __shfl_xor(tmax, 16));
        tm = fmaxf(tm, __shfl_xor(tm, 32));
        const float mnew = fmaxf(mrunb, tm);
        const float corr = exp2f(mrunb - mnew);
        lrunb *= corr;
        #pragma unroll
        for (int dt=0;dt<4;dt++)
          #pragma unroll
          for (int r=0;r<4;r++) ctxb[dt][r] *= corr;
        mrunb = mnew;
      }
      float psum = 0.f;
      #pragma unroll
      for (int kt=0;kt<4;kt++){
        float p0 = exp2f(scb[kt][0] - mrunb);
        float p1 = exp2f(scb[kt][1] - mrunb);
        float p2 = exp2f(scb[kt][2] - mrunb);
        float p3 = exp2f(scb[kt][3] - mrunb);
        psum += (p0 + p1) + (p2 + p3);
        union { short4v s; __hip_bfloat162 h[2]; } u;
        u.h[0] = __float22bfloat162_rn(make_float2(p0, p1));
        u.h[1] = __float22bfloat162_rn(make_float2(p2, p3));
        pab[kt] = u.s;
      }
      lrunb += psum;
    }

    // PV: ctx^T[d][q] += V^T[d][k] * P^T[k][q]; V-frags shared by both frags
    const char* vsb = (const char*)&kvbuf[1][team][buf][0][0];
    __builtin_amdgcn_s_setprio(1);
#if HAVE_MFMA16
    #pragma unroll
    for (int dt=0;dt<4;dt++){
      const int dr = dt*16 + fr;
      const int dswz = dr & 7;
      #pragma unroll
      for (int kt=0;kt<4;kt++){
        const int voff = (((kt*2 + (g>>1)) ^ dswz) << 4) + ((g&1)*8);
        short4v va = *reinterpret_cast<const short4v*>(vsb + dr*128 + voff);
        ctxa[dt] = __builtin_amdgcn_mfma_f32_16x16x16bf16_1k(va, paa[kt], ctxa[dt], 0,0,0);
        ctxb[dt] = __builtin_amdgcn_mfma_f32_16x16x16bf16_1k(va, pab[kt], ctxb[dt], 0,0,0);
      }
    }
#else
    #pragma unroll
    for (int f=0;f<2;f++){
      union { short8 s8; unsigned u[4]; } bfa, bfb;
      #pragma unroll
      for (int m=0;m<4;m++){
        const int srcl = ((g&1)*2 + (m>>1))*16 + fr;
        union { short4v s; unsigned u[2]; } ca0, ca1, cb0, cb1;
        ca0.s = paa[f*2+0]; ca1.s = paa[f*2+1];
        cb0.s = pab[f*2+0]; cb1.s = pab[f*2+1];
        unsigned a0 = __shfl((int)ca0.u[m&1], srcl);
        unsigned a1 = __shfl((int)ca1.u[m&1], srcl);
        bfa.u[m] = (g >> 1) ? a1 : a0;
        unsigned b0 = __shfl((int)cb0.u[m&1], srcl);
        unsigned b1 = __shfl((int)cb1.u[m&1], srcl);
        bfb.u[m] = (g >> 1) ? b1 : b0;
      }
      #pragma unroll
      for (int dt=0;dt<4;dt++){
        const int dr = dt*16 + fr;
        const int vswz = (dr & 7) << 4;
        short8 va = *reinterpret_cast<const short8*>(
            vsb + dr*128 + ((g*16 + f*64) ^ vswz));
        ctxa[dt] = __builtin_amdgcn_mfma_f32_16x16x32_bf16(va, bfa.s8, ctxa[dt], 0,0,0);
        ctxb[dt] = __builtin_amdgcn_mfma_f32_16x16x32_bf16(va, bfb.s8, ctxb[dt], 0,0,0);
      }
    }
#endif
    __builtin_amdgcn_s_setprio(0);

    __syncthreads();
    buf ^= 1;
  }

  // ---- epilogue: reduce per-lane partial lrun across the 4 g-lanes ----
  lruna += __shfl_xor(lruna, 16);
  lruna += __shfl_xor(lruna, 32);
  lrunb += __shfl_xor(lrunb, 16);
  lrunb += __shfl_xor(lrunb, 32);

  // ---- merge the two teams' partial (m, l, ctx) via LDS ----
  float* mctx = (float*)&kvbuf[0][0][0][0][0];
  const int rowA = wt*32 + fr, rowB = rowA + 16;
  if (team == 1){
    #pragma unroll
    for (int dt=0;dt<4;dt++){
      *reinterpret_cast<f32x4*>(&mctx[rowA*72 + dt*16 + g*4]) = ctxa[dt];
      *reinterpret_cast<f32x4*>(&mctx[rowB*72 + dt*16 + g*4]) = ctxb[dt];
    }
    ml[rowA][0] = mruna; ml[rowA][1] = lruna;
    ml[rowB][0] = mrunb; ml[rowB][1] = lrunb;
  }
  __syncthreads();
  if (team == 0){
    {
      const float m1 = ml[rowA][0], l1 = ml[rowA][1];
      const float m  = fmaxf(mruna, m1);
      const float s0 = exp2f(mruna - m), s1 = exp2f(m1 - m);
      const float rl = 1.f / (lruna*s0 + l1*s1);
      #pragma unroll
      for (int dt=0;dt<4;dt++){
        f32x4 c1 = *reinterpret_cast<const f32x4*>(&mctx[rowA*72 + dt*16 + g*4]);
        short4v o;
        #pragma unroll
        for (int r=0;r<4;r++) o[r] = f2b((ctxa[dt][r]*s0 + c1[r]*s1) * rl);
        *reinterpret_cast<short4v*>(
            Ctx + (size_t)(b*SEQ + qa)*D_MODEL + h*D_KK + dt*16 + g*4) = o;
      }
    }
    {
      const float m1 = ml[rowB][0], l1 = ml[rowB][1];
      const float m  = fmaxf(mrunb, m1);
      const float s0 = exp2f(mrunb - m), s1 = exp2f(m1 - m);
      const float rl = 1.f / (lrunb*s0 + l1*s1);
      #pragma unroll
      for (int dt=0;dt<4;dt++){
        f32x4 c1 = *reinterpret_cast<const f32x4*>(&mctx[rowB*72 + dt*16 + g*4]);
        short4v o;
        #pragma unroll
        for (int r=0;r<4;r++) o[r] = f2b((ctxb[dt][r]*s0 + c1[r]*s1) * rl);
        *reinterpret_cast<short4v*>(
            Ctx + (size_t)(b*SEQ + qb)*D_MODEL + h*D_KK + dt*16 + g*4) = o;
      }
    }
  }
}

// ---------------- launch ----------------
extern "C" void kernel_launch(void* const* d_in, const int* in_sizes, int n_in,
                              void* d_out, int out_size, void* d_ws, size_t ws_size,
                              hipStream_t stream) {
  const float* x    = (const float*)d_in[0];
  const int*   mask = (const int*)  d_in[1];
  const float* wq   = (const float*)d_in[2];
  const float* bq   = (const float*)d_in[3];
  const float* wk   = (const float*)d_in[4];
  const float* bk   = (const float*)d_in[5];
  const float* wv   = (const float*)d_in[6];
  const float* bv   = (const float*)d_in[7];
  const float* wo   = (const float*)d_in[8];
  const float* bo   = (const float*)d_in[9];
  const float* rel  = (const float*)d_in[10];

  const size_t NX = (size_t)NTOK * D_MODEL;      // 4194304
  const size_t NW = (size_t)D_MODEL * D_MODEL;   // 1048576
  if (ws_size < (NX + 4*NW + 4*NX) * sizeof(short)) return;
  short* xb   = (short*)d_ws;
  short* wqb  = xb  + NX;
  short* wkb  = wqb + NW;
  short* wvb  = wkb + NW;
  short* wob  = wvb + NW;
  short* Qb   = wob + NW;
  short* Kb   = Qb  + NX;
  short* Vtg  = Kb  + NX;   // V transposed per head: [B*H][64][SEQ]
  short* Ctxb = Vtg + NX;

  cvt_all_kernel<<<8192, 256, 0, stream>>>(x, wq, wk, wv, wo, xb);

  qkv_gemm_kernel<<<dim3(8, 32, 3), 256, 0, stream>>>(
      xb, wqb, wkb, wvb, bq, bk, bv, Qb, Kb, Vtg);

  attn_kernel<<<512, 512, 0, stream>>>(Qb, Kb, Vtg, mask, rel, Ctxb);

  out_gemm_kernel<<<dim3(16, 32), 256, 0, stream>>>(Ctxb, wob, bo, (float*)d_out);
}